// Round 1
// baseline (829.553 us; speedup 1.0000x reference)
//
#include <hip/hip_runtime.h>

#define F_IN 512
#define HID 128
#define CLS 64
#define EPS 1e-5f

// ---------------- column stats (BatchNorm, biased var) ----------------
__global__ __launch_bounds__(256) void col_stats_k(const float* __restrict__ x,
                                                   float* __restrict__ sum,
                                                   float* __restrict__ sumsq,
                                                   int n, int rows_per_block) {
    int c = threadIdx.x;                       // 0..255, handles c and c+256
    int r0 = blockIdx.x * rows_per_block;
    int r1 = min(n, r0 + rows_per_block);
    float s0 = 0.f, q0 = 0.f, s1 = 0.f, q1 = 0.f;
    for (int r = r0; r < r1; ++r) {
        const float* xr = x + (size_t)r * F_IN;
        float v0 = xr[c], v1 = xr[c + 256];
        s0 += v0; q0 += v0 * v0;
        s1 += v1; q1 += v1 * v1;
    }
    if (r0 < r1) {
        atomicAdd(&sum[c], s0);       atomicAdd(&sumsq[c], q0);
        atomicAdd(&sum[c + 256], s1); atomicAdd(&sumsq[c + 256], q1);
    }
}

__global__ void finalize_stats_k(const float* __restrict__ sum,
                                 const float* __restrict__ sumsq,
                                 float* __restrict__ mu, float* __restrict__ rinv,
                                 int n) {
    int c = threadIdx.x;   // 512 threads
    float m = sum[c] / (float)n;
    float v = sumsq[c] / (float)n - m * m;
    mu[c] = m;
    rinv[c] = rsqrtf(v + EPS);
}

// ---------------- weight packing (sign bits + per-col beta) ----------------
// sig layout: transposed, sig[w * ncols + j], bit l of word w = (W[(w*64+l)*ncols + j] > 0)
__global__ __launch_bounds__(64) void pack_w1_k(const float* __restrict__ W,
                                                unsigned long long* __restrict__ sig,
                                                float* __restrict__ beta) {
    int j = blockIdx.x;    // 0..127
    int l = threadIdx.x;   // 0..63
    float asum = 0.f;
    for (int w = 0; w < 8; ++w) {
        float v = W[(size_t)(w * 64 + l) * HID + j];
        asum += fabsf(v);
        unsigned long long b = __ballot(v > 0.0f);
        if (l == 0) sig[w * HID + j] = b;
    }
    for (int m = 32; m >= 1; m >>= 1) asum += __shfl_xor(asum, m);
    if (l == 0) beta[j] = asum * (1.0f / 512.0f);
}

__global__ __launch_bounds__(64) void pack_w2_k(const float* __restrict__ W,
                                                unsigned long long* __restrict__ sig,
                                                float* __restrict__ beta) {
    int j = blockIdx.x;    // 0..63
    int l = threadIdx.x;
    float asum = 0.f;
    for (int w = 0; w < 2; ++w) {
        float v = W[(size_t)(w * 64 + l) * CLS + j];
        asum += fabsf(v);
        unsigned long long b = __ballot(v > 0.0f);
        if (l == 0) sig[w * CLS + j] = b;
    }
    for (int m = 32; m >= 1; m >>= 1) asum += __shfl_xor(asum, m);
    if (l == 0) beta[j] = asum * (1.0f / 128.0f);
}

// ---------------- degree / dinv ----------------
__global__ __launch_bounds__(256) void deg_k(const int* __restrict__ col,
                                             int* __restrict__ deg, int e) {
    int i = blockIdx.x * blockDim.x + threadIdx.x;
    if (i < e) atomicAdd(&deg[col[i]], 1);
}

__global__ __launch_bounds__(256) void dinv_k(const int* __restrict__ deg,
                                              float* __restrict__ dinv, int n) {
    int i = blockIdx.x * blockDim.x + threadIdx.x;
    if (i < n) dinv[i] = rsqrtf((float)deg[i] + 1.0f);  // +1 self-loop
}

// ---------------- layer 1: fused binarize + XNOR-GEMM ----------------
// one wave per node; 4 nodes per 256-thread block
__global__ __launch_bounds__(256) void bin1_gemm1_k(const float* __restrict__ x,
                                                    const float* __restrict__ mu,
                                                    const float* __restrict__ rinv,
                                                    const unsigned long long* __restrict__ sigW,
                                                    const float* __restrict__ beta,
                                                    float* __restrict__ h1, int n) {
    int tid = threadIdx.x;
    int wave = tid >> 6, l = tid & 63;
    int i = blockIdx.x * 4 + wave;
    if (i >= n) return;
    const float* xr = x + (size_t)i * F_IN;
    unsigned long long sx[8];
    float asum = 0.f;
#pragma unroll
    for (int w = 0; w < 8; ++w) {
        int f = w * 64 + l;
        float t = xr[f] - mu[f];
        asum += fabsf(t) * rinv[f];
        sx[w] = __ballot(t > 0.0f);
    }
    for (int m = 32; m >= 1; m >>= 1) asum += __shfl_xor(asum, m);
    float a = asum * (1.0f / 512.0f);
#pragma unroll
    for (int half = 0; half < 2; ++half) {
        int j = l + half * 64;
        int cnt = 0;
#pragma unroll
        for (int w = 0; w < 8; ++w) cnt += __popcll(sx[w] ^ sigW[w * HID + j]);
        float dot = (float)(512 - 2 * cnt);
        h1[(size_t)i * HID + j] = a * beta[j] * dot;
    }
}

// ---------------- aggregation layer 1 ----------------
__global__ __launch_bounds__(256) void agg1_init_k(const float* __restrict__ h1,
                                                   const float* __restrict__ dinv,
                                                   const float* __restrict__ b1,
                                                   float* __restrict__ out1, int n) {
    size_t idx = (size_t)blockIdx.x * 256 + threadIdx.x;
    if (idx < (size_t)n * HID) {
        int i = (int)(idx >> 7);
        int f = (int)(idx & 127);
        float w = dinv[i];
        out1[idx] = w * w * h1[idx] + b1[f];
    }
}

__global__ __launch_bounds__(256) void agg1_edge_k(const float* __restrict__ h1,
                                                   const int* __restrict__ row,
                                                   const int* __restrict__ col,
                                                   const float* __restrict__ dinv,
                                                   float* __restrict__ out1, int e) {
    int eid = blockIdx.x * 2 + (threadIdx.x >> 7);  // 2 edges / block
    int f = threadIdx.x & 127;
    if (eid < e) {
        int r = row[eid], c = col[eid];
        float w = dinv[r] * dinv[c];
        atomicAdd(&out1[(size_t)c * HID + f], w * h1[(size_t)r * HID + f]);
    }
}

// ---------------- layer 2: fused binarize + XNOR-GEMM ----------------
__global__ __launch_bounds__(256) void bin2_gemm2_k(const float* __restrict__ y,
                                                    const unsigned long long* __restrict__ sigW,
                                                    const float* __restrict__ beta,
                                                    float* __restrict__ h2, int n) {
    int tid = threadIdx.x;
    int wave = tid >> 6, l = tid & 63;
    int i = blockIdx.x * 4 + wave;
    if (i >= n) return;
    const float* yr = y + (size_t)i * HID;
    float v0 = yr[l], v1 = yr[l + 64];
    float asum = fabsf(v0) + fabsf(v1);
    unsigned long long s0 = __ballot(v0 > 0.f);
    unsigned long long s1 = __ballot(v1 > 0.f);
    for (int m = 32; m >= 1; m >>= 1) asum += __shfl_xor(asum, m);
    float a = asum * (1.0f / 128.0f);
    int cnt = __popcll(s0 ^ sigW[0 * CLS + l]) + __popcll(s1 ^ sigW[1 * CLS + l]);
    h2[(size_t)i * CLS + l] = a * beta[l] * (float)(128 - 2 * cnt);
}

// ---------------- aggregation layer 2 (accumulate into d_out) ----------------
__global__ __launch_bounds__(256) void agg2_init_k(const float* __restrict__ h2,
                                                   const float* __restrict__ dinv,
                                                   const float* __restrict__ b2,
                                                   float* __restrict__ out, int n) {
    size_t idx = (size_t)blockIdx.x * 256 + threadIdx.x;
    if (idx < (size_t)n * CLS) {
        int i = (int)(idx >> 6);
        int f = (int)(idx & 63);
        float w = dinv[i];
        out[idx] = w * w * h2[idx] + b2[f];
    }
}

__global__ __launch_bounds__(256) void agg2_edge_k(const float* __restrict__ h2,
                                                   const int* __restrict__ row,
                                                   const int* __restrict__ col,
                                                   const float* __restrict__ dinv,
                                                   float* __restrict__ out, int e) {
    int eid = blockIdx.x * 4 + (threadIdx.x >> 6);  // 4 edges / block
    int f = threadIdx.x & 63;
    if (eid < e) {
        int r = row[eid], c = col[eid];
        float w = dinv[r] * dinv[c];
        atomicAdd(&out[(size_t)c * CLS + f], w * h2[(size_t)r * CLS + f]);
    }
}

// ---------------- log_softmax over 64 classes, in-place ----------------
__global__ __launch_bounds__(256) void logsoftmax_k(float* __restrict__ out, int n) {
    int tid = threadIdx.x;
    int wave = tid >> 6, l = tid & 63;
    int i = blockIdx.x * 4 + wave;
    if (i >= n) return;
    float v = out[(size_t)i * CLS + l];
    float m = v;
    for (int k = 32; k >= 1; k >>= 1) m = fmaxf(m, __shfl_xor(m, k));
    float ev = expf(v - m);
    float s = ev;
    for (int k = 32; k >= 1; k >>= 1) s += __shfl_xor(s, k);
    out[(size_t)i * CLS + l] = v - m - logf(s);
}

// ---------------- launch ----------------
extern "C" void kernel_launch(void* const* d_in, const int* in_sizes, int n_in,
                              void* d_out, int out_size, void* d_ws, size_t ws_size,
                              hipStream_t stream) {
    const float* x  = (const float*)d_in[0];
    const int*   ei = (const int*)d_in[1];
    const float* W1 = (const float*)d_in[2];
    const float* b1 = (const float*)d_in[3];
    const float* W2 = (const float*)d_in[4];
    const float* b2 = (const float*)d_in[5];
    float* out = (float*)d_out;

    const int n = in_sizes[0] / F_IN;   // 50000
    const int e = in_sizes[1] / 2;      // 800000
    const int* row = ei;
    const int* col = ei + e;

    // ---- workspace bump allocator (256B aligned) ----
    char* w = (char*)d_ws;
    size_t off = 0;
    auto alloc = [&](size_t bytes) {
        void* p = w + off;
        off += (bytes + 255) & ~(size_t)255;
        return p;
    };
    float* colsum   = (float*)alloc(F_IN * 4);        // zeroed
    float* colsumsq = (float*)alloc(F_IN * 4);        // zeroed
    int*   deg      = (int*)alloc((size_t)n * 4);     // zeroed
    size_t zero_bytes = off;                          // contiguous zero region
    float* mu    = (float*)alloc(F_IN * 4);
    float* rinv  = (float*)alloc(F_IN * 4);
    float* dinv  = (float*)alloc((size_t)n * 4);
    float* beta1 = (float*)alloc(HID * 4);
    unsigned long long* sig1 = (unsigned long long*)alloc(HID * 8 * 8);
    float* beta2 = (float*)alloc(CLS * 4);
    unsigned long long* sig2 = (unsigned long long*)alloc(CLS * 2 * 8);
    float* h1   = (float*)alloc((size_t)n * HID * 4);
    float* out1 = (float*)alloc((size_t)n * HID * 4);
    float* h2   = (float*)alloc((size_t)n * CLS * 4);
    (void)ws_size;

    hipMemsetAsync(d_ws, 0, zero_bytes, stream);

    int rpb = (n + 1023) / 1024;
    col_stats_k<<<1024, 256, 0, stream>>>(x, colsum, colsumsq, n, rpb);
    finalize_stats_k<<<1, F_IN, 0, stream>>>(colsum, colsumsq, mu, rinv, n);
    pack_w1_k<<<HID, 64, 0, stream>>>(W1, sig1, beta1);
    pack_w2_k<<<CLS, 64, 0, stream>>>(W2, sig2, beta2);
    deg_k<<<(e + 255) / 256, 256, 0, stream>>>(col, deg, e);
    dinv_k<<<(n + 255) / 256, 256, 0, stream>>>(deg, dinv, n);

    bin1_gemm1_k<<<(n + 3) / 4, 256, 0, stream>>>(x, mu, rinv, sig1, beta1, h1, n);
    agg1_init_k<<<(int)(((size_t)n * HID + 255) / 256), 256, 0, stream>>>(h1, dinv, b1, out1, n);
    agg1_edge_k<<<(e + 1) / 2, 256, 0, stream>>>(h1, row, col, dinv, out1, e);

    bin2_gemm2_k<<<(n + 3) / 4, 256, 0, stream>>>(out1, sig2, beta2, h2, n);
    agg2_init_k<<<(int)(((size_t)n * CLS + 255) / 256), 256, 0, stream>>>(h2, dinv, b2, out, n);
    agg2_edge_k<<<(e + 3) / 4, 256, 0, stream>>>(h2, row, col, dinv, out, e);

    logsoftmax_k<<<(n + 3) / 4, 256, 0, stream>>>(out, n);
}

// Round 2
// 488.682 us; speedup vs baseline: 1.6975x; 1.6975x over previous
//
#include <hip/hip_runtime.h>

#define F_IN 512
#define HID 128
#define CLS 64
#define EPS 1e-5f

// ---------------- column stats (BatchNorm, biased var) ----------------
__global__ __launch_bounds__(256) void col_stats_k(const float* __restrict__ x,
                                                   float* __restrict__ sum,
                                                   float* __restrict__ sumsq,
                                                   int n, int rows_per_block) {
    int c = threadIdx.x;                       // 0..255, handles c and c+256
    int r0 = blockIdx.x * rows_per_block;
    int r1 = min(n, r0 + rows_per_block);
    float s0 = 0.f, q0 = 0.f, s1 = 0.f, q1 = 0.f;
    for (int r = r0; r < r1; ++r) {
        const float* xr = x + (size_t)r * F_IN;
        float v0 = xr[c], v1 = xr[c + 256];
        s0 += v0; q0 += v0 * v0;
        s1 += v1; q1 += v1 * v1;
    }
    if (r0 < r1) {
        atomicAdd(&sum[c], s0);       atomicAdd(&sumsq[c], q0);
        atomicAdd(&sum[c + 256], s1); atomicAdd(&sumsq[c + 256], q1);
    }
}

__global__ void finalize_stats_k(const float* __restrict__ sum,
                                 const float* __restrict__ sumsq,
                                 float* __restrict__ mu, float* __restrict__ rinv,
                                 int n) {
    int c = threadIdx.x;   // 512 threads
    float m = sum[c] / (float)n;
    float v = sumsq[c] / (float)n - m * m;
    mu[c] = m;
    rinv[c] = rsqrtf(v + EPS);
}

// ---------------- weight packing (sign bits + per-col beta) ----------------
__global__ __launch_bounds__(64) void pack_w1_k(const float* __restrict__ W,
                                                unsigned long long* __restrict__ sig,
                                                float* __restrict__ beta) {
    int j = blockIdx.x;    // 0..127
    int l = threadIdx.x;   // 0..63
    float asum = 0.f;
    for (int w = 0; w < 8; ++w) {
        float v = W[(size_t)(w * 64 + l) * HID + j];
        asum += fabsf(v);
        unsigned long long b = __ballot(v > 0.0f);
        if (l == 0) sig[w * HID + j] = b;
    }
    for (int m = 32; m >= 1; m >>= 1) asum += __shfl_xor(asum, m);
    if (l == 0) beta[j] = asum * (1.0f / 512.0f);
}

__global__ __launch_bounds__(64) void pack_w2_k(const float* __restrict__ W,
                                                unsigned long long* __restrict__ sig,
                                                float* __restrict__ beta) {
    int j = blockIdx.x;    // 0..63
    int l = threadIdx.x;
    float asum = 0.f;
    for (int w = 0; w < 2; ++w) {
        float v = W[(size_t)(w * 64 + l) * CLS + j];
        asum += fabsf(v);
        unsigned long long b = __ballot(v > 0.0f);
        if (l == 0) sig[w * CLS + j] = b;
    }
    for (int m = 32; m >= 1; m >>= 1) asum += __shfl_xor(asum, m);
    if (l == 0) beta[j] = asum * (1.0f / 128.0f);
}

// ---------------- degree / dinv ----------------
__global__ __launch_bounds__(256) void deg_k(const int* __restrict__ col,
                                             int* __restrict__ deg, int e) {
    int i = blockIdx.x * blockDim.x + threadIdx.x;
    if (i < e) atomicAdd(&deg[col[i]], 1);
}

__global__ __launch_bounds__(256) void dinv_k(const int* __restrict__ deg,
                                              float* __restrict__ dinv, int n) {
    int i = blockIdx.x * blockDim.x + threadIdx.x;
    if (i < n) dinv[i] = rsqrtf((float)deg[i] + 1.0f);  // +1 self-loop
}

// ---------------- exclusive scan of deg -> CSR offsets (n=50K, 3 kernels) ----
__global__ __launch_bounds__(256) void scan_partial_k(const int* __restrict__ deg,
                                                      int* __restrict__ bsum, int n) {
    __shared__ int lds[256];
    int i = blockIdx.x * 256 + threadIdx.x;
    lds[threadIdx.x] = (i < n) ? deg[i] : 0;
    __syncthreads();
    for (int s = 128; s > 0; s >>= 1) {
        if (threadIdx.x < s) lds[threadIdx.x] += lds[threadIdx.x + s];
        __syncthreads();
    }
    if (threadIdx.x == 0) bsum[blockIdx.x] = lds[0];
}

__global__ __launch_bounds__(256) void scan_bsum_k(const int* __restrict__ bsum,
                                                   int* __restrict__ boff, int nb) {
    // single block, nb <= 256
    __shared__ int lds[256];
    int t = threadIdx.x;
    int v = (t < nb) ? bsum[t] : 0;
    lds[t] = v;
    __syncthreads();
    for (int s = 1; s < 256; s <<= 1) {
        int add = (t >= s) ? lds[t - s] : 0;
        __syncthreads();
        lds[t] += add;
        __syncthreads();
    }
    if (t < nb) boff[t] = lds[t] - v;   // exclusive
}

__global__ __launch_bounds__(256) void scan_final_k(const int* __restrict__ deg,
                                                    const int* __restrict__ boff,
                                                    int* __restrict__ offs,
                                                    int* __restrict__ cursor, int n) {
    __shared__ int lds[256];
    int t = threadIdx.x;
    int i = blockIdx.x * 256 + t;
    int v = (i < n) ? deg[i] : 0;
    lds[t] = v;
    __syncthreads();
    for (int s = 1; s < 256; s <<= 1) {
        int add = (t >= s) ? lds[t - s] : 0;
        __syncthreads();
        lds[t] += add;
        __syncthreads();
    }
    int excl = lds[t] - v + boff[blockIdx.x];
    if (i < n) { offs[i] = excl; cursor[i] = excl; }
}

// ---------------- CSR fill: bucket edges by dst, store {row, norm} ----------
__global__ __launch_bounds__(256) void fill_k(const int* __restrict__ row,
                                              const int* __restrict__ col,
                                              const float* __restrict__ dinv,
                                              int* __restrict__ cursor,
                                              int2* __restrict__ csr, int e) {
    int i = blockIdx.x * blockDim.x + threadIdx.x;
    if (i < e) {
        int r = row[i], c = col[i];
        int p = atomicAdd(&cursor[c], 1);
        float w = dinv[r] * dinv[c];
        csr[p] = make_int2(r, __float_as_int(w));
    }
}

// ---------------- layer 1: fused binarize + XNOR-GEMM ----------------
__global__ __launch_bounds__(256) void bin1_gemm1_k(const float* __restrict__ x,
                                                    const float* __restrict__ mu,
                                                    const float* __restrict__ rinv,
                                                    const unsigned long long* __restrict__ sigW,
                                                    const float* __restrict__ beta,
                                                    float* __restrict__ h1, int n) {
    int tid = threadIdx.x;
    int wave = tid >> 6, l = tid & 63;
    int i = blockIdx.x * 4 + wave;
    if (i >= n) return;
    const float* xr = x + (size_t)i * F_IN;
    unsigned long long sx[8];
    float asum = 0.f;
#pragma unroll
    for (int w = 0; w < 8; ++w) {
        int f = w * 64 + l;
        float t = xr[f] - mu[f];
        asum += fabsf(t) * rinv[f];
        sx[w] = __ballot(t > 0.0f);
    }
    for (int m = 32; m >= 1; m >>= 1) asum += __shfl_xor(asum, m);
    float a = asum * (1.0f / 512.0f);
#pragma unroll
    for (int half = 0; half < 2; ++half) {
        int j = l + half * 64;
        int cnt = 0;
#pragma unroll
        for (int w = 0; w < 8; ++w) cnt += __popcll(sx[w] ^ sigW[w * HID + j]);
        float dot = (float)(512 - 2 * cnt);
        h1[(size_t)i * HID + j] = a * beta[j] * dot;
    }
}

// ---------------- agg layer1 (CSR gather) + BinActive + XNOR-GEMM2 -> h2 ----
__global__ __launch_bounds__(256) void agg1_fused_k(const float* __restrict__ h1,
                                                    const int2* __restrict__ csr,
                                                    const int* __restrict__ offs,
                                                    const int* __restrict__ deg,
                                                    const float* __restrict__ dinv,
                                                    const float* __restrict__ b1,
                                                    const unsigned long long* __restrict__ sig2,
                                                    const float* __restrict__ beta2,
                                                    float* __restrict__ h2, int n) {
    int tid = threadIdx.x;
    int wave = tid >> 6, l = tid & 63;
    int i = blockIdx.x * 4 + wave;
    if (i >= n) return;
    float di = dinv[i];
    float acc0 = di * di * h1[(size_t)i * HID + l]      + b1[l];
    float acc1 = di * di * h1[(size_t)i * HID + 64 + l] + b1[64 + l];
    int off = offs[i], d = deg[i];
    for (int k = 0; k < d; ++k) {
        int2 ew = csr[off + k];          // wave-uniform -> broadcast
        int r = ew.x;
        float w = __int_as_float(ew.y);
        acc0 += w * h1[(size_t)r * HID + l];
        acc1 += w * h1[(size_t)r * HID + 64 + l];
    }
    // BinActive over 128 features (2 per lane)
    float asum = fabsf(acc0) + fabsf(acc1);
    for (int m = 32; m >= 1; m >>= 1) asum += __shfl_xor(asum, m);
    float a = asum * (1.0f / 128.0f);
    unsigned long long s0 = __ballot(acc0 > 0.f);
    unsigned long long s1 = __ballot(acc1 > 0.f);
    // XNOR-GEMM2: lane l computes class l
    int cnt = __popcll(s0 ^ sig2[l]) + __popcll(s1 ^ sig2[CLS + l]);
    h2[(size_t)i * CLS + l] = a * beta2[l] * (float)(128 - 2 * cnt);
}

// ---------------- agg layer2 (CSR gather) + bias + log_softmax -> out -------
__global__ __launch_bounds__(256) void agg2_fused_k(const float* __restrict__ h2,
                                                    const int2* __restrict__ csr,
                                                    const int* __restrict__ offs,
                                                    const int* __restrict__ deg,
                                                    const float* __restrict__ dinv,
                                                    const float* __restrict__ b2,
                                                    float* __restrict__ out, int n) {
    int tid = threadIdx.x;
    int wave = tid >> 6, l = tid & 63;
    int i = blockIdx.x * 4 + wave;
    if (i >= n) return;
    float di = dinv[i];
    float acc = di * di * h2[(size_t)i * CLS + l] + b2[l];
    int off = offs[i], d = deg[i];
    for (int k = 0; k < d; ++k) {
        int2 ew = csr[off + k];
        int r = ew.x;
        float w = __int_as_float(ew.y);
        acc += w * h2[(size_t)r * CLS + l];
    }
    // log_softmax over 64 classes (one per lane)
    float m = acc;
    for (int k = 32; k >= 1; k >>= 1) m = fmaxf(m, __shfl_xor(m, k));
    float ev = __expf(acc - m);
    float s = ev;
    for (int k = 32; k >= 1; k >>= 1) s += __shfl_xor(s, k);
    out[(size_t)i * CLS + l] = acc - m - __logf(s);
}

// ---------------- launch ----------------
extern "C" void kernel_launch(void* const* d_in, const int* in_sizes, int n_in,
                              void* d_out, int out_size, void* d_ws, size_t ws_size,
                              hipStream_t stream) {
    const float* x  = (const float*)d_in[0];
    const int*   ei = (const int*)d_in[1];
    const float* W1 = (const float*)d_in[2];
    const float* b1 = (const float*)d_in[3];
    const float* W2 = (const float*)d_in[4];
    const float* b2 = (const float*)d_in[5];
    float* out = (float*)d_out;

    const int n = in_sizes[0] / F_IN;   // 50000
    const int e = in_sizes[1] / 2;      // 800000
    const int* row = ei;
    const int* col = ei + e;

    // ---- workspace bump allocator (256B aligned) ----
    char* w = (char*)d_ws;
    size_t off = 0;
    auto alloc = [&](size_t bytes) {
        void* p = w + off;
        off += (bytes + 255) & ~(size_t)255;
        return p;
    };
    float* colsum   = (float*)alloc(F_IN * 4);        // zeroed
    float* colsumsq = (float*)alloc(F_IN * 4);        // zeroed
    int*   deg      = (int*)alloc((size_t)n * 4);     // zeroed
    size_t zero_bytes = off;                          // contiguous zero region
    float* mu    = (float*)alloc(F_IN * 4);
    float* rinv  = (float*)alloc(F_IN * 4);
    float* dinv  = (float*)alloc((size_t)n * 4);
    float* beta1 = (float*)alloc(HID * 4);
    unsigned long long* sig1 = (unsigned long long*)alloc(HID * 8 * 8);
    float* beta2 = (float*)alloc(CLS * 4);
    unsigned long long* sig2 = (unsigned long long*)alloc(CLS * 2 * 8);
    int*   offs   = (int*)alloc((size_t)n * 4);
    int*   cursor = (int*)alloc((size_t)n * 4);
    int*   bsum   = (int*)alloc(256 * 4);
    int*   boff   = (int*)alloc(256 * 4);
    int2*  csr    = (int2*)alloc((size_t)e * 8);
    float* h1     = (float*)alloc((size_t)n * HID * 4);
    float* h2     = (float*)alloc((size_t)n * CLS * 4);
    (void)ws_size;

    hipMemsetAsync(d_ws, 0, zero_bytes, stream);

    int rpb = (n + 1023) / 1024;
    col_stats_k<<<1024, 256, 0, stream>>>(x, colsum, colsumsq, n, rpb);
    finalize_stats_k<<<1, F_IN, 0, stream>>>(colsum, colsumsq, mu, rinv, n);
    pack_w1_k<<<HID, 64, 0, stream>>>(W1, sig1, beta1);
    pack_w2_k<<<CLS, 64, 0, stream>>>(W2, sig2, beta2);
    deg_k<<<(e + 255) / 256, 256, 0, stream>>>(col, deg, e);
    dinv_k<<<(n + 255) / 256, 256, 0, stream>>>(deg, dinv, n);

    int nb = (n + 255) / 256;           // 196 <= 256
    scan_partial_k<<<nb, 256, 0, stream>>>(deg, bsum, n);
    scan_bsum_k<<<1, 256, 0, stream>>>(bsum, boff, nb);
    scan_final_k<<<nb, 256, 0, stream>>>(deg, boff, offs, cursor, n);
    fill_k<<<(e + 255) / 256, 256, 0, stream>>>(row, col, dinv, cursor, csr, e);

    bin1_gemm1_k<<<(n + 3) / 4, 256, 0, stream>>>(x, mu, rinv, sig1, beta1, h1, n);
    agg1_fused_k<<<(n + 3) / 4, 256, 0, stream>>>(h1, csr, offs, deg, dinv, b1, sig2, beta2, h2, n);
    agg2_fused_k<<<(n + 3) / 4, 256, 0, stream>>>(h2, csr, offs, deg, dinv, b2, out, n);
}